// Round 12
// baseline (1038.520 us; speedup 1.0000x reference)
//
#include <hip/hip_runtime.h>
#include <hip/hip_bf16.h>
#include <stdint.h>

// QuantizedLinear: Y[M][N] = scale * (X[M][K] @ W[N][K]^T) + bias[N]
// M=8192, K=4096, N=16384. X fp32, W int32 (harness widens int8), out fp32.
// Round 12: 32x32x16 MFMA shape (2382 TF ceiling vs 2075 for 16x16x32,
// half the MFMA instruction count). LDS layout, swizzle, staging, vmcnt
// ring, super-tile mapping, and the r11 DS_READ||MFMA interleave are all
// UNCHANGED — only fragment addressing, MFMA shape, and epilogue C/D
// mapping (col=lane&31, row=(reg&3)+8*(reg>>2)+4*(lane>>5), m74/m101).

typedef __attribute__((ext_vector_type(4))) float f32x4;
typedef __attribute__((ext_vector_type(16))) float f32x16;
typedef __attribute__((ext_vector_type(4))) int i32x4;
typedef __attribute__((ext_vector_type(8))) short bf16x8s;
typedef __attribute__((ext_vector_type(4))) unsigned int u32x4;

__device__ __forceinline__ uint32_t f2bf_rne(float f) {
  uint32_t x = __float_as_uint(f);
  return (x + 0x7FFFu + ((x >> 16) & 1u)) >> 16;
}
__device__ __forceinline__ uint32_t pk2_rne(float lo, float hi) {
  return f2bf_rne(lo) | (f2bf_rne(hi) << 16);
}
__device__ __forceinline__ uint32_t pk2_trunc(float lo, float hi) {
  return (__float_as_uint(lo) >> 16) | (__float_as_uint(hi) & 0xFFFF0000u);
}

#define GLOAD_LDS16(g, l)                                        \
  __builtin_amdgcn_global_load_lds(                              \
      (const __attribute__((address_space(1))) void*)(g),        \
      (__attribute__((address_space(3))) void*)(l), 16, 0, 0)

// ---------------- conversion kernels (NT loads: inputs are read-once) ------
__global__ __launch_bounds__(256) void conv_x_kernel(
    const float* __restrict__ x, uint16_t* __restrict__ out, int n8) {
  const int stride = blockDim.x * gridDim.x;
  for (int i = blockIdx.x * blockDim.x + threadIdx.x; i < n8; i += stride) {
    f32x4 v0 = __builtin_nontemporal_load((const f32x4*)x + i * 2);
    f32x4 v1 = __builtin_nontemporal_load((const f32x4*)x + i * 2 + 1);
    u32x4 o;
    o.x = pk2_rne(v0.x, v0.y);
    o.y = pk2_rne(v0.z, v0.w);
    o.z = pk2_rne(v1.x, v1.y);
    o.w = pk2_rne(v1.z, v1.w);
    ((u32x4*)out)[i] = o;
  }
}

__global__ __launch_bounds__(256) void conv_w_kernel(
    const int32_t* __restrict__ w, uint16_t* __restrict__ out, int n8) {
  const int stride = blockDim.x * gridDim.x;
  for (int i = blockIdx.x * blockDim.x + threadIdx.x; i < n8; i += stride) {
    i32x4 v0 = __builtin_nontemporal_load((const i32x4*)w + i * 2);
    i32x4 v1 = __builtin_nontemporal_load((const i32x4*)w + i * 2 + 1);
    u32x4 o;
    o.x = pk2_trunc((float)v0.x, (float)v0.y);
    o.y = pk2_trunc((float)v0.z, (float)v0.w);
    o.z = pk2_trunc((float)v1.x, (float)v1.y);
    o.w = pk2_trunc((float)v1.z, (float)v1.w);
    ((u32x4*)out)[i] = o;
  }
}

// ---------------- 256x256 GEMM, 32x32x16 interleaved pipeline -------------
// LDS: buf b at b*65536; A at +0, B at +32768; K-half kk at kk*16384 =
// [256 rows][32 bf16] (64 B rows). Swizzle: chunk ^= (row>>1)&3 (involution),
// staged via pre-swizzled GLOBAL source + linear LDS dest (rule #21).
// 32x32x16 operands: lane supplies row=lane&31, k=(lane>>5)*8+e. Per epoch
// per wave: 8 A-frags (4 mblks x 2 ksteps) + 4 B-frags (2 nblks x 2 ksteps)
// = 12 ds_read_b128 (same as r11), 16 MFMAs (was 32, 2x FLOP each).

#define PIN() __builtin_amdgcn_sched_barrier(0)

#define BARRIER()                 \
  PIN();                          \
  __builtin_amdgcn_s_barrier();   \
  PIN()

#define WAIT4  asm volatile("s_waitcnt vmcnt(4)" ::: "memory"); PIN()
#define WAIT0  asm volatile("s_waitcnt vmcnt(0)" ::: "memory"); PIN()
#define WAITL0 asm volatile("s_waitcnt lgkmcnt(0)" ::: "memory"); PIN()

#define STAGE(mat_base, koffb, ldsbase)                                      \
  {                                                                          \
    GLOAD_LDS16((mat_base) + (size_t)srow * RSB + (koffb) + skch,            \
                (ldsbase) + tid * 16);                                       \
    GLOAD_LDS16((mat_base) + (size_t)(srow + 128) * RSB + (koffb) + skch,    \
                (ldsbase) + 8192 + tid * 16);                                \
  }

#define ABLK(buf, kk) ((buf) + (kk) * 16384)
#define BBLK(buf, kk) ((buf) + 32768 + (kk) * 16384)

// inline-asm ds_read_b128 — invisible to the compiler's waitcnt pass
#define DSR(dst, addr, OFF)                                                  \
  asm volatile("ds_read_b128 %0, %1 offset:" OFF : "=v"(dst) : "v"(addr))

// k0 MFMAs use frags [0..3]/[0..1]; k1 MFMAs use [4..7]/[2..3]
#define MFMA_K0(av, bv, m, n)                                                \
  acc[m][n] = __builtin_amdgcn_mfma_f32_32x32x16_bf16(                       \
      av[m], bv[n], acc[m][n], 0, 0, 0);
#define MFMA_K1(av, bv, m, n)                                                \
  acc[m][n] = __builtin_amdgcn_mfma_f32_32x32x16_bf16(                       \
      av[4 + (m)], bv[2 + (n)], acc[m][n], 0, 0, 0);

// prologue-only: 12 batched reads (first fill). blkoff = buffer+khalf byte off
#define READ12(da, db, blkoff)                                               \
  {                                                                          \
    uint32_t _a0 = aoff_k0 + (blkoff), _a1 = aoff_k1 + (blkoff);             \
    uint32_t _b0 = boff_k0 + (blkoff), _b1 = boff_k1 + (blkoff);             \
    DSR(da[0], _a0, "0");    DSR(da[1], _a0, "2048");                        \
    DSR(da[2], _a0, "4096"); DSR(da[3], _a0, "6144");                        \
    DSR(da[4], _a1, "0");    DSR(da[5], _a1, "2048");                        \
    DSR(da[6], _a1, "4096"); DSR(da[7], _a1, "6144");                        \
    DSR(db[0], _b0, "0");    DSR(db[1], _b0, "2048");                        \
    DSR(db[2], _b1, "0");    DSR(db[3], _b1, "2048");                        \
  }

// One epoch: 16 MFMAs on (av,bv) interleaved with the 12 ds_reads filling
// (xa,xb) for the NEXT epoch (prefetch target block at blkoff).
#define EPOCH_ILV(av, bv, xa, xb, blkoff)                                    \
  {                                                                          \
    uint32_t _a0 = aoff_k0 + (blkoff), _a1 = aoff_k1 + (blkoff);             \
    uint32_t _b0 = boff_k0 + (blkoff), _b1 = boff_k1 + (blkoff);             \
    __builtin_amdgcn_s_setprio(1);                                           \
    DSR(xa[0], _a0, "0");    DSR(xa[1], _a0, "2048");   PIN();               \
    MFMA_K0(av, bv, 0, 0); MFMA_K0(av, bv, 0, 1); MFMA_K0(av, bv, 1, 0);     \
    PIN();                                                                   \
    DSR(xa[2], _a0, "4096"); DSR(xa[3], _a0, "6144");   PIN();               \
    MFMA_K0(av, bv, 1, 1); MFMA_K0(av, bv, 2, 0); MFMA_K0(av, bv, 2, 1);     \
    PIN();                                                                   \
    DSR(xa[4], _a1, "0");    DSR(xa[5], _a1, "2048");   PIN();               \
    MFMA_K0(av, bv, 3, 0); MFMA_K0(av, bv, 3, 1);       PIN();               \
    DSR(xa[6], _a1, "4096"); DSR(xa[7], _a1, "6144");   PIN();               \
    MFMA_K1(av, bv, 0, 0); MFMA_K1(av, bv, 0, 1); MFMA_K1(av, bv, 1, 0);     \
    PIN();                                                                   \
    DSR(xb[0], _b0, "0");    DSR(xb[1], _b0, "2048");   PIN();               \
    MFMA_K1(av, bv, 1, 1); MFMA_K1(av, bv, 2, 0); MFMA_K1(av, bv, 2, 1);     \
    PIN();                                                                   \
    DSR(xb[2], _b1, "0");    DSR(xb[3], _b1, "2048");   PIN();               \
    MFMA_K1(av, bv, 3, 0); MFMA_K1(av, bv, 3, 1);                            \
    __builtin_amdgcn_s_setprio(0);                                           \
  }

// last epoch: plain 16 MFMAs, no prefetch
#define MFMA16ALL(av, bv)                                                    \
  __builtin_amdgcn_s_setprio(1);                                             \
  MFMA_K0(av, bv, 0, 0); MFMA_K0(av, bv, 0, 1); MFMA_K0(av, bv, 1, 0);       \
  MFMA_K0(av, bv, 1, 1); MFMA_K0(av, bv, 2, 0); MFMA_K0(av, bv, 2, 1);       \
  MFMA_K0(av, bv, 3, 0); MFMA_K0(av, bv, 3, 1);                              \
  MFMA_K1(av, bv, 0, 0); MFMA_K1(av, bv, 0, 1); MFMA_K1(av, bv, 1, 0);       \
  MFMA_K1(av, bv, 1, 1); MFMA_K1(av, bv, 2, 0); MFMA_K1(av, bv, 2, 1);       \
  MFMA_K1(av, bv, 3, 0); MFMA_K1(av, bv, 3, 1);                              \
  __builtin_amdgcn_s_setprio(0);

__global__ __launch_bounds__(512, 2) void qlinear_gemm_256_kernel(
    const uint16_t* __restrict__ Xb,  // [M][K] bf16
    const uint16_t* __restrict__ Wb,  // [N][K] bf16
    const float* __restrict__ scalep,
    const float* __restrict__ bias,
    float* __restrict__ Y)
{
  constexpr int N = 16384, K = 4096;
  constexpr int RSB = K * 2;   // panel row stride, bytes
  constexpr int NT = K / 64;   // 64 K-tiles

  extern __shared__ __align__(16) char lds[];  // 131072 B

  const int tid  = threadIdx.x;
  const int lane = tid & 63;
  const int wid  = tid >> 6;   // 0..7
  const int wm   = wid >> 2;   // 0..1  (M-half of block)
  const int wn   = wid & 3;    // 0..3  (N-quarter of block)

  const int rl  = lane & 31;   // operand row (A) / col (B)
  const int l5  = lane >> 5;   // k-group bit
  const int xv  = (rl >> 1) & 3;  // chunk swizzle XOR value

  const int srow = tid >> 2;                              // 0..127
  const int skch = ((tid & 3) ^ ((tid >> 3) & 3)) * 16;   // pre-swizzled src

  // ---- 2D super-tile mapping (round 6): XCD-private 16x16 patches ----
  const int bid = blockIdx.x;
  const int xcd = bid & 7;
  const int l   = bid >> 3;          // 0..255
  const int bm  = (xcd & 1) * 16 + (l >> 4);
  const int bn  = (xcd >> 1) * 16 + (l & 15);

  f32x16 acc[4][2];
#pragma unroll
  for (int i = 0; i < 4; ++i)
#pragma unroll
    for (int j = 0; j < 2; ++j) acc[i][j] = (f32x16)0.f;

  bf16x8s pa[8], qa[8], pb[4], qb[4];

  const char* Xp = (const char*)Xb + (size_t)(bm * 256) * RSB;
  const char* Wp = (const char*)Wb + (size_t)(bn * 256) * RSB;

  // LDS fragment base addresses (u32 byte addresses).
  // A frag (mblk, kstep): addr = aoff_kS + blkoff + mblk*2048, where
  // row = wm*128 + mblk*32 + rl, chunk_phys = (kstep*2 + l5) ^ xv.
  const uint32_t ldsb = (uint32_t)(uintptr_t)(void*)lds;
  const uint32_t aoff_k0 =
      ldsb + (uint32_t)((wm * 128 + rl) * 64 + ((0 + l5) ^ xv) * 16);
  const uint32_t aoff_k1 =
      ldsb + (uint32_t)((wm * 128 + rl) * 64 + ((2 + l5) ^ xv) * 16);
  const uint32_t boff_k0 =
      ldsb + (uint32_t)(32768 + (wn * 64 + rl) * 64 + ((0 + l5) ^ xv) * 16);
  const uint32_t boff_k1 =
      ldsb + (uint32_t)(32768 + (wn * 64 + rl) * 64 + ((2 + l5) ^ xv) * 16);

  // ---- prologue: stage (0,k0),(0,k1),(1,k0); confirm (0,*); read (0,k0) ----
  STAGE(Xp, 0,   ABLK(lds, 0));
  STAGE(Wp, 0,   BBLK(lds, 0));
  STAGE(Xp, 64,  ABLK(lds, 1));
  STAGE(Wp, 64,  BBLK(lds, 1));
  STAGE(Xp, 128, ABLK(lds + 65536, 0));
  STAGE(Wp, 128, BBLK(lds + 65536, 0));
  WAIT4;        // 12 -> 4: confirms (0,k0) and (0,k1)
  BARRIER();
  READ12(pa, pb, 0u);   // (0,k0); loop's first WAITL0 drains these

  // ---- main loop: tiles 0 .. NT-3 ----
  for (int t = 0; t <= NT - 3; ++t) {
    const uint32_t cur = (uint32_t)(t & 1) << 16;
    const uint32_t nxt = cur ^ 65536u;
    char* cb = lds + cur;
    char* nb = lds + nxt;
    const size_t k1n = (size_t)(t + 1) * 128;
    const size_t k2n = (size_t)(t + 2) * 128;
    // epoch A: MFMA (t,k0)=P; interleave-prefetch Q<-(t,k1); stage (t+1,k1)
    STAGE(Xp, k1n + 64, ABLK(nb, 1));
    STAGE(Wp, k1n + 64, BBLK(nb, 1));
    WAITL0;     // P frags landed (issued interleaved during prev epoch)
    EPOCH_ILV(pa, pb, qa, qb, cur + 16384u);
    WAIT4;      // confirms (t+1,k0), staged one epoch ago
    BARRIER();
    // epoch B: MFMA (t,k1)=Q; interleave-prefetch P<-(t+1,k0); stage (t+2,k0)
    STAGE(Xp, k2n, ABLK(cb, 0));
    STAGE(Wp, k2n, BBLK(cb, 0));
    WAITL0;
    EPOCH_ILV(qa, qb, pa, pb, nxt);
    WAIT4;      // confirms (t+1,k1)
    BARRIER();
  }

  // ---- tail: tile NT-2 (even; cur=buf0, nxt=buf1) ----
  {
    const uint32_t cur = (uint32_t)((NT - 2) & 1) << 16;
    const uint32_t nxt = cur ^ 65536u;
    char* nb = lds + nxt;
    const size_t k1n = (size_t)(NT - 1) * 128;
    // epoch A: MFMA (NT-2,k0); prefetch (NT-2,k1); stage (NT-1,k1)
    STAGE(Xp, k1n + 64, ABLK(nb, 1));
    STAGE(Wp, k1n + 64, BBLK(nb, 1));
    WAITL0;
    EPOCH_ILV(pa, pb, qa, qb, cur + 16384u);
    WAIT4;      // confirms (NT-1,k0)
    BARRIER();
    // epoch B: MFMA (NT-2,k1); prefetch (NT-1,k0); no stage
    WAITL0;
    EPOCH_ILV(qa, qb, pa, pb, nxt);
    WAIT0;      // confirms (NT-1,k1)
    BARRIER();
    // tile NT-1, epoch A: MFMA (NT-1,k0); prefetch (NT-1,k1)
    WAITL0;
    EPOCH_ILV(pa, pb, qa, qb, nxt + 16384u);
    // tile NT-1, epoch B: MFMA (NT-1,k1)
    WAITL0;
    MFMA16ALL(qa, qb);
  }

  // ---- epilogue: y = scale*acc + bias ----
  // 32x32 C/D layout: col = lane&31, row = (reg&3) + 8*(reg>>2) + 4*(lane>>5)
  // [m74/m101-verified]
  const float s = scalep[0];
  float bv[2];
#pragma unroll
  for (int n = 0; n < 2; ++n)
    bv[n] = bias[bn * 256 + wn * 64 + n * 32 + rl];

#pragma unroll
  for (int m = 0; m < 4; ++m) {
#pragma unroll
    for (int q = 0; q < 4; ++q) {
#pragma unroll
      for (int r = 0; r < 4; ++r) {
        const int reg  = q * 4 + r;
        const int grow = bm * 256 + wm * 128 + m * 32 + r + 8 * q + 4 * l5;
        float* yp = Y + (size_t)grow * N + bn * 256 + wn * 64 + rl;
        yp[0]  = s * acc[m][0][reg] + bv[0];
        yp[32] = s * acc[m][1][reg] + bv[1];
      }
    }
  }
}

// ---------------- fallback: fused kernel (if ws too small) ----------------
#define BM 128
#define BN 128
#define BK 64
#define LDKF (BK * 2)

__global__ __launch_bounds__(256, 2) void qlinear_fused_kernel(
    const float* __restrict__ X, const int32_t* __restrict__ W,
    const float* __restrict__ scalep, const float* __restrict__ bias,
    float* __restrict__ Y)
{
  constexpr int N = 16384, K = 4096;
  __shared__ __align__(16) char slds[(BM + BN) * LDKF];
  char* As = slds;
  char* Bs = slds + BM * LDKF;
  const int tid = threadIdx.x, lane = tid & 63, wid = tid >> 6;
  const int wr = wid >> 1, wc = wid & 1;
  const int nwg = gridDim.x, cpx = nwg >> 3, bid = blockIdx.x;
  const int swz = (bid & 7) * cpx + (bid >> 3);
  const int ntn = N / BN, bm = swz / ntn, bn = swz % ntn;
  const int r16 = lane & 15, g4 = lane >> 4;
  f32x4 acc[4][4];
#pragma unroll
  for (int i = 0; i < 4; ++i)
#pragma unroll
    for (int j = 0; j < 4; ++j) acc[i][j] = (f32x4)0.f;
  const float* Abase = X + (size_t)(bm * BM) * K;
  const int32_t* Bbase = W + (size_t)(bn * BN) * K;
  const int stg_col = (tid & 7) * 8;
  for (int kt = 0; kt < K / BK; ++kt) {
    const int kb = kt * BK;
    if (kt) __syncthreads();
#pragma unroll
    for (int i = 0; i < 4; ++i) {
      const int row = i * 32 + (tid >> 3);
      const float* p = Abase + (size_t)row * K + kb + stg_col;
      f32x4 v0 = *(const f32x4*)p;
      f32x4 v1 = *(const f32x4*)(p + 4);
      u32x4 o = {pk2_rne(v0.x, v0.y), pk2_rne(v0.z, v0.w),
                 pk2_rne(v1.x, v1.y), pk2_rne(v1.z, v1.w)};
      int byte = (row * LDKF + stg_col * 2) ^ ((row & 7) << 4);
      *(u32x4*)(As + byte) = o;
    }
#pragma unroll
    for (int i = 0; i < 4; ++i) {
      const int row = i * 32 + (tid >> 3);
      const int32_t* p = Bbase + (size_t)row * K + kb + stg_col;
      i32x4 v0 = *(const i32x4*)p;
      i32x4 v1 = *(const i32x4*)(p + 4);
      u32x4 o = {pk2_trunc((float)v0.x, (float)v0.y),
                 pk2_trunc((float)v0.z, (float)v0.w),
                 pk2_trunc((float)v1.x, (float)v1.y),
                 pk2_trunc((float)v1.z, (float)v1.w)};
      int byte = (row * LDKF + stg_col * 2) ^ ((row & 7) << 4);
      *(u32x4*)(Bs + byte) = o;
    }
    __syncthreads();
#pragma unroll
    for (int kk = 0; kk < 2; ++kk) {
      bf16x8s af[4], bfr[4];
#pragma unroll
      for (int mi = 0; mi < 4; ++mi) {
        const int row = wr * 64 + mi * 16 + r16;
        int byte = (row * LDKF + kk * 64 + g4 * 16) ^ ((row & 7) << 4);
        af[mi] = *(const bf16x8s*)(As + byte);
      }
#pragma unroll
      for (int ni = 0; ni < 4; ++ni) {
        const int row = wc * 64 + ni * 16 + r16;
        int byte = (row * LDKF + kk * 64 + g4 * 16) ^ ((row & 7) << 4);
        bfr[ni] = *(const bf16x8s*)(Bs + byte);
      }
#pragma unroll
      for (int mi = 0; mi < 4; ++mi)
#pragma unroll
        for (int ni = 0; ni < 4; ++ni)
          acc[mi][ni] = __builtin_amdgcn_mfma_f32_16x16x32_bf16(
              af[mi], bfr[ni], acc[mi][ni], 0, 0, 0);
    }
  }
  const float s = scalep[0];
  float bv[4];
#pragma unroll
  for (int ni = 0; ni < 4; ++ni)
    bv[ni] = bias[bn * BN + wc * 64 + ni * 16 + r16];
#pragma unroll
  for (int mi = 0; mi < 4; ++mi) {
    const int grow0 = bm * BM + wr * 64 + mi * 16 + g4 * 4;
#pragma unroll
    for (int r = 0; r < 4; ++r) {
      float* yp = Y + (size_t)(grow0 + r) * N + bn * BN + wc * 64 + r16;
#pragma unroll
      for (int ni = 0; ni < 4; ++ni)
        yp[ni * 16] = s * acc[mi][ni][r] + bv[ni];
    }
  }
}

extern "C" void kernel_launch(void* const* d_in, const int* in_sizes, int n_in,
                              void* d_out, int out_size, void* d_ws, size_t ws_size,
                              hipStream_t stream) {
  const float*   x  = (const float*)d_in[0];
  const int32_t* w  = (const int32_t*)d_in[1];
  const float*   sc = (const float*)d_in[2];
  const float*   bs = (const float*)d_in[3];
  float*         y  = (float*)d_out;

  constexpr size_t M = 8192, N = 16384, K = 4096;
  const size_t xb_elems = M * K;   // 64 MB bf16
  const size_t wb_elems = N * K;   // 128 MB bf16
  const size_t need = (xb_elems + wb_elems) * 2;

  if (ws_size >= need) {
    uint16_t* xb = (uint16_t*)d_ws;
    uint16_t* wb = xb + xb_elems;
    hipFuncSetAttribute((const void*)qlinear_gemm_256_kernel,
                        hipFuncAttributeMaxDynamicSharedMemorySize, 131072);
    conv_x_kernel<<<2048, 256, 0, stream>>>(x, xb, (int)(xb_elems / 8));
    conv_w_kernel<<<2048, 256, 0, stream>>>(w, wb, (int)(wb_elems / 8));
    qlinear_gemm_256_kernel<<<2048, 512, 131072, stream>>>(xb, wb, sc, bs, y);
  } else {
    qlinear_fused_kernel<<<8192, 256, 0, stream>>>(x, w, sc, bs, y);
  }
}